// Round 1
// baseline (4959.218 us; speedup 1.0000x reference)
//
#include <hip/hip_runtime.h>
#include <hip/hip_bf16.h>
#include <math.h>

// Problem constants (from reference): N=100000, E=3200000, F_IN=128, G=64, A=32
// Layer dims: 128 -> 16 -> 64 -> 32, then pool -> 32 -> 64 -> 32(out)

#define THREADS 256

__global__ void k_init_deg(float* deg, int N) {
    int i = blockIdx.x * blockDim.x + threadIdx.x;
    if (i < N) deg[i] = 1.0f;  // self-loop
}

__global__ void k_deg_count(const int* __restrict__ dst, float* __restrict__ deg, int E) {
    int e = blockIdx.x * blockDim.x + threadIdx.x;
    if (e < E) atomicAdd(&deg[dst[e]], 1.0f);
}

__global__ void k_make_dinv(float* deg, int N) {
    int i = blockIdx.x * blockDim.x + threadIdx.x;
    if (i < N) deg[i] = (float)(1.0 / sqrt((double)deg[i]));
}

__global__ void k_zero(float* p, long long count) {
    long long i = (long long)blockIdx.x * blockDim.x + threadIdx.x;
    if (i < count) p[i] = 0.0f;
}

// H[n][j] = sum_k X[n][k] * W[k][j]   (W staged in LDS; 256/J rows per block)
template<int K, int J>
__global__ void k_gemm_nodes(const float* __restrict__ X, const float* __restrict__ W,
                             float* __restrict__ H, int N) {
    __shared__ float Ws[K * J];
    for (int i = threadIdx.x; i < K * J; i += blockDim.x) Ws[i] = W[i];
    __syncthreads();
    const int ROWS = THREADS / J;
    int row = blockIdx.x * ROWS + threadIdx.x / J;
    int j = threadIdx.x % J;
    if (row >= N) return;
    const float* xr = X + (size_t)row * K;
    float acc = 0.0f;
#pragma unroll 8
    for (int k = 0; k < K; ++k) acc += xr[k] * Ws[k * J + j];
    H[(size_t)row * J + j] = acc;
}

// One thread per (edge, 4-feature chunk): gather h[src], scale, atomic-scatter to agg[dst]
template<int F>
__global__ void k_edge_scatter(const int* __restrict__ src, const int* __restrict__ dst,
                               const float* __restrict__ dinv, const float* __restrict__ H,
                               float* __restrict__ agg, int E) {
    const int CH = F / 4;
    int gid = blockIdx.x * blockDim.x + threadIdx.x;
    if (gid >= E * CH) return;
    int e = gid / CH;
    int c = gid % CH;
    int s = src[e];
    int d = dst[e];
    float coef = dinv[s] * dinv[d];
    const float4 hv = *(const float4*)(H + (size_t)s * F + c * 4);
    float* ap = agg + (size_t)d * F + c * 4;
    atomicAdd(ap + 0, hv.x * coef);
    atomicAdd(ap + 1, hv.y * coef);
    atomicAdd(ap + 2, hv.z * coef);
    atomicAdd(ap + 3, hv.w * coef);
}

// out[n][f] = (relu?)(agg[n][f] + H[n][f]*dinv[n]^2 + b[f])
template<int F, bool RELU>
__global__ void k_finalize(const float* __restrict__ agg, const float* __restrict__ H,
                           const float* __restrict__ dinv, const float* __restrict__ b,
                           float* __restrict__ out, int N) {
    long long gid = (long long)blockIdx.x * blockDim.x + threadIdx.x;
    if (gid >= (long long)N * F) return;
    int n = (int)(gid / F);
    int f = (int)(gid % F);
    float di = dinv[n];
    float v = agg[gid] + H[gid] * di * di + b[f];
    if (RELU) v = fmaxf(v, 0.0f);
    out[gid] = v;
}

// batch is sorted: block g binary-searches its [start,end) node range, mean over 32 features
__global__ void k_pool_mean(const float* __restrict__ h, const int* __restrict__ batch,
                            int N, float* __restrict__ pooled) {
    int g = blockIdx.x;
    // lower_bound(batch, g) and lower_bound(batch, g+1)
    int lo = 0, hi = N;
    while (lo < hi) { int m = (lo + hi) >> 1; if (batch[m] < g) lo = m + 1; else hi = m; }
    int start = lo;
    lo = start; hi = N;
    while (lo < hi) { int m = (lo + hi) >> 1; if (batch[m] < g + 1) lo = m + 1; else hi = m; }
    int end = lo;

    __shared__ float partial[THREADS];
    int f = threadIdx.x % 32;
    int grp = threadIdx.x / 32;  // 8 node-lanes
    float acc = 0.0f;
    for (int n = start + grp; n < end; n += 8) acc += h[(size_t)n * 32 + f];
    partial[threadIdx.x] = acc;
    __syncthreads();
    if (threadIdx.x < 32) {
        float s = 0.0f;
#pragma unroll
        for (int t = 0; t < 8; ++t) s += partial[t * 32 + f];
        int cnt = end - start;
        pooled[g * 32 + f] = s / (float)(cnt > 0 ? cnt : 1);
    }
}

// a = relu(pooled @ Wa + ba) [G,64]; out = tanh(a @ Wo + bo) [G,32]
__global__ void k_head(const float* __restrict__ pooled, const float* __restrict__ Wa,
                       const float* __restrict__ ba, const float* __restrict__ Wo,
                       const float* __restrict__ bo, float* __restrict__ out) {
    int g = blockIdx.x;
    int j = threadIdx.x;  // 64 threads
    __shared__ float p[32];
    __shared__ float a[64];
    if (j < 32) p[j] = pooled[g * 32 + j];
    __syncthreads();
    float acc = ba[j];
#pragma unroll
    for (int k = 0; k < 32; ++k) acc += p[k] * Wa[k * 64 + j];
    a[j] = fmaxf(acc, 0.0f);
    __syncthreads();
    if (j < 32) {
        float acc2 = bo[j];
#pragma unroll
        for (int k = 0; k < 64; ++k) acc2 += a[k] * Wo[k * 32 + j];
        out[g * 32 + j] = tanhf(acc2);
    }
}

static inline int cdiv(long long a, int b) { return (int)((a + b - 1) / b); }

extern "C" void kernel_launch(void* const* d_in, const int* in_sizes, int n_in,
                              void* d_out, int out_size, void* d_ws, size_t ws_size,
                              hipStream_t stream) {
    const float* x     = (const float*)d_in[0];   // [N,128]
    const int*   edge  = (const int*)d_in[1];     // [2,E] row-major: src then dst
    const int*   batch = (const int*)d_in[2];     // [N], sorted
    const float* W1 = (const float*)d_in[3];  const float* b1 = (const float*)d_in[4];
    const float* W2 = (const float*)d_in[5];  const float* b2 = (const float*)d_in[6];
    const float* W3 = (const float*)d_in[7];  const float* b3 = (const float*)d_in[8];
    const float* Wa = (const float*)d_in[9];  const float* ba = (const float*)d_in[10];
    const float* Wo = (const float*)d_in[11]; const float* bo = (const float*)d_in[12];

    const int E = in_sizes[1] / 2;
    const int N = in_sizes[2];
    const int G = 64;

    const int* srcp = edge;
    const int* dstp = edge + E;

    // Workspace layout (floats): dinv[N] | bufB[N*64] | bufC[N*64] | bufA[N*64] | pooled[G*32]
    float* ws    = (float*)d_ws;
    float* dinv  = ws;
    float* bufB  = dinv + N;              // GEMM output h
    float* bufC  = bufB + (size_t)N * 64; // aggregation buffer
    float* bufA  = bufC + (size_t)N * 64; // activation (layer input/output)
    float* pooled = bufA + (size_t)N * 64;

    // Degrees -> dinv
    k_init_deg<<<cdiv(N, THREADS), THREADS, 0, stream>>>(dinv, N);
    k_deg_count<<<cdiv(E, THREADS), THREADS, 0, stream>>>(dstp, dinv, E);
    k_make_dinv<<<cdiv(N, THREADS), THREADS, 0, stream>>>(dinv, N);

    // ---- Layer 1: 128 -> 16, relu ----
    k_zero<<<cdiv((long long)N * 16, THREADS), THREADS, 0, stream>>>(bufC, (long long)N * 16);
    k_gemm_nodes<128, 16><<<cdiv(N, THREADS / 16), THREADS, 0, stream>>>(x, W1, bufB, N);
    k_edge_scatter<16><<<cdiv((long long)E * 4, THREADS), THREADS, 0, stream>>>(srcp, dstp, dinv, bufB, bufC, E);
    k_finalize<16, true><<<cdiv((long long)N * 16, THREADS), THREADS, 0, stream>>>(bufC, bufB, dinv, b1, bufA, N);

    // ---- Layer 2: 16 -> 64, relu ----
    k_zero<<<cdiv((long long)N * 64, THREADS), THREADS, 0, stream>>>(bufC, (long long)N * 64);
    k_gemm_nodes<16, 64><<<cdiv(N, THREADS / 64), THREADS, 0, stream>>>(bufA, W2, bufB, N);
    k_edge_scatter<64><<<cdiv((long long)E * 16, THREADS), THREADS, 0, stream>>>(srcp, dstp, dinv, bufB, bufC, E);
    k_finalize<64, true><<<cdiv((long long)N * 64, THREADS), THREADS, 0, stream>>>(bufC, bufB, dinv, b2, bufA, N);

    // ---- Layer 3: 64 -> 32, no relu ----
    k_zero<<<cdiv((long long)N * 32, THREADS), THREADS, 0, stream>>>(bufC, (long long)N * 32);
    k_gemm_nodes<64, 32><<<cdiv(N, THREADS / 32), THREADS, 0, stream>>>(bufA, W3, bufB, N);
    k_edge_scatter<32><<<cdiv((long long)E * 8, THREADS), THREADS, 0, stream>>>(srcp, dstp, dinv, bufB, bufC, E);
    k_finalize<32, false><<<cdiv((long long)N * 32, THREADS), THREADS, 0, stream>>>(bufC, bufB, dinv, b3, bufA, N);

    // ---- Pool + head ----
    k_pool_mean<<<G, THREADS, 0, stream>>>(bufA, batch, N, pooled);
    k_head<<<G, 64, 0, stream>>>(pooled, Wa, ba, Wo, bo, (float*)d_out);
}

// Round 2
// 1266.812 us; speedup vs baseline: 3.9147x; 3.9147x over previous
//
#include <hip/hip_runtime.h>
#include <hip/hip_bf16.h>
#include <math.h>

// ActorGNN: N=100000 nodes, E=3200000 edges, layers 128->16->64->32, pool G=64, head 32->64->32
// Strategy R2: CSR (by dst) pull-based aggregation — no float atomics.

#define THREADS 256
#define SCAN_T 1024

__global__ void k_zero_int(int* p, int n) {
    int i = blockIdx.x * blockDim.x + threadIdx.x;
    if (i < n) p[i] = 0;
}

__global__ void k_count(const int* __restrict__ dst, int* __restrict__ counts, int E) {
    int e = blockIdx.x * blockDim.x + threadIdx.x;
    if (e < E) atomicAdd(&counts[dst[e]], 1);
}

// Single-block exclusive scan over counts[N]; also writes cursor (=rowptr) and dinv.
__global__ void k_scan(const int* __restrict__ counts, int* __restrict__ rowptr,
                       int* __restrict__ cursor, float* __restrict__ dinv, int N) {
    __shared__ int sums[SCAN_T];
    int t = threadIdx.x;
    int chunk = (N + SCAN_T - 1) / SCAN_T;
    int beg = t * chunk;
    int end = min(beg + chunk, N);
    int s = 0;
    for (int i = beg; i < end; ++i) s += counts[i];
    sums[t] = s;
    __syncthreads();
    // Hillis-Steele inclusive scan over 1024 block sums
    for (int off = 1; off < SCAN_T; off <<= 1) {
        int v = (t >= off) ? sums[t - off] : 0;
        __syncthreads();
        sums[t] += v;
        __syncthreads();
    }
    int run = (t == 0) ? 0 : sums[t - 1];
    for (int i = beg; i < end; ++i) {
        rowptr[i] = run;
        cursor[i] = run;
        int c = counts[i];
        dinv[i] = (float)(1.0 / sqrt((double)(c + 1)));  // +1 self-loop
        run += c;
    }
    if (t == SCAN_T - 1) rowptr[N] = run;
}

__global__ void k_fill(const int* __restrict__ src, const int* __restrict__ dst,
                       int* __restrict__ cursor, int* __restrict__ csr_src, int E) {
    int e = blockIdx.x * blockDim.x + threadIdx.x;
    if (e < E) {
        int d = dst[e];
        int pos = atomicAdd(&cursor[d], 1);
        csr_src[pos] = src[e];
    }
}

// Hs[n][j] = (sum_k X[n][k] * W[k][j]) * dinv[n]   (W staged in LDS; 256/J rows/block)
template<int K, int J>
__global__ void k_gemm_nodes(const float* __restrict__ X, const float* __restrict__ W,
                             const float* __restrict__ dinv, float* __restrict__ H, int N) {
    __shared__ float Ws[K * J];
    for (int i = threadIdx.x; i < K * J; i += blockDim.x) Ws[i] = W[i];
    __syncthreads();
    const int ROWS = THREADS / J;
    int row = blockIdx.x * ROWS + threadIdx.x / J;
    int j = threadIdx.x % J;
    if (row >= N) return;
    const float4* xr4 = (const float4*)(X + (size_t)row * K);
    float acc = 0.0f;
#pragma unroll
    for (int k4 = 0; k4 < K / 4; ++k4) {
        float4 xv = xr4[k4];  // broadcast across the J threads of this row
        acc += xv.x * Ws[(k4 * 4 + 0) * J + j];
        acc += xv.y * Ws[(k4 * 4 + 1) * J + j];
        acc += xv.z * Ws[(k4 * 4 + 2) * J + j];
        acc += xv.w * Ws[(k4 * 4 + 3) * J + j];
    }
    H[(size_t)row * J + j] = acc * dinv[row];
}

// Pull aggregation: out[n][f] = act( dinv[n]*(sum_{e->n} Hs[src_e][f] + Hs[n][f]) + b[f] )
template<int F, bool RELU>
__global__ void k_pull(const int* __restrict__ rowptr, const int* __restrict__ csr_src,
                       const float* __restrict__ dinv, const float* __restrict__ Hs,
                       const float* __restrict__ b, float* __restrict__ out, int N) {
    const int NODES = THREADS / F;
    int node = blockIdx.x * NODES + threadIdx.x / F;
    int f = threadIdx.x % F;
    if (node >= N) return;
    int beg = rowptr[node];
    int end = rowptr[node + 1];
    float acc = 0.0f;
    int i = beg;
    int sNext = (i < end) ? csr_src[i] : 0;  // prefetch index one iteration ahead
    for (; i < end; ++i) {
        int s = sNext;
        if (i + 1 < end) sNext = csr_src[i + 1];
        acc += Hs[(size_t)s * F + f];
    }
    float di = dinv[node];
    float v = di * (acc + Hs[(size_t)node * F + f]) + b[f];
    if (RELU) v = fmaxf(v, 0.0f);
    out[(size_t)node * F + f] = v;
}

// batch is sorted: block g binary-searches its [start,end) node range, mean over 32 features
__global__ void k_pool_mean(const float* __restrict__ h, const int* __restrict__ batch,
                            int N, float* __restrict__ pooled) {
    int g = blockIdx.x;
    int lo = 0, hi = N;
    while (lo < hi) { int m = (lo + hi) >> 1; if (batch[m] < g) lo = m + 1; else hi = m; }
    int start = lo;
    lo = start; hi = N;
    while (lo < hi) { int m = (lo + hi) >> 1; if (batch[m] < g + 1) lo = m + 1; else hi = m; }
    int end = lo;

    __shared__ float partial[THREADS];
    int f = threadIdx.x % 32;
    int grp = threadIdx.x / 32;
    float acc = 0.0f;
    for (int n = start + grp; n < end; n += 8) acc += h[(size_t)n * 32 + f];
    partial[threadIdx.x] = acc;
    __syncthreads();
    if (threadIdx.x < 32) {
        float s = 0.0f;
#pragma unroll
        for (int t = 0; t < 8; ++t) s += partial[t * 32 + f];
        int cnt = end - start;
        pooled[g * 32 + f] = s / (float)(cnt > 0 ? cnt : 1);
    }
}

// a = relu(pooled @ Wa + ba) [G,64]; out = tanh(a @ Wo + bo) [G,32]
__global__ void k_head(const float* __restrict__ pooled, const float* __restrict__ Wa,
                       const float* __restrict__ ba, const float* __restrict__ Wo,
                       const float* __restrict__ bo, float* __restrict__ out) {
    int g = blockIdx.x;
    int j = threadIdx.x;  // 64 threads
    __shared__ float p[32];
    __shared__ float a[64];
    if (j < 32) p[j] = pooled[g * 32 + j];
    __syncthreads();
    float acc = ba[j];
#pragma unroll
    for (int k = 0; k < 32; ++k) acc += p[k] * Wa[k * 64 + j];
    a[j] = fmaxf(acc, 0.0f);
    __syncthreads();
    if (j < 32) {
        float acc2 = bo[j];
#pragma unroll
        for (int k = 0; k < 64; ++k) acc2 += a[k] * Wo[k * 32 + j];
        out[g * 32 + j] = tanhf(acc2);
    }
}

static inline int cdiv(long long a, int b) { return (int)((a + b - 1) / b); }
static inline size_t align256(size_t x) { return (x + 255) & ~(size_t)255; }

extern "C" void kernel_launch(void* const* d_in, const int* in_sizes, int n_in,
                              void* d_out, int out_size, void* d_ws, size_t ws_size,
                              hipStream_t stream) {
    const float* x     = (const float*)d_in[0];   // [N,128]
    const int*   edge  = (const int*)d_in[1];     // [2,E]: src row then dst row
    const int*   batch = (const int*)d_in[2];     // [N], sorted
    const float* W1 = (const float*)d_in[3];  const float* b1 = (const float*)d_in[4];
    const float* W2 = (const float*)d_in[5];  const float* b2 = (const float*)d_in[6];
    const float* W3 = (const float*)d_in[7];  const float* b3 = (const float*)d_in[8];
    const float* Wa = (const float*)d_in[9];  const float* ba = (const float*)d_in[10];
    const float* Wo = (const float*)d_in[11]; const float* bo = (const float*)d_in[12];

    const int E = in_sizes[1] / 2;
    const int N = in_sizes[2];
    const int G = 64;

    const int* srcp = edge;
    const int* dstp = edge + E;

    // Workspace layout (256B-aligned regions)
    char* base = (char*)d_ws;
    size_t off = 0;
    float* dinv    = (float*)(base + off); off = align256(off + sizeof(float) * N);
    int*   counts  = (int*)  (base + off); off = align256(off + sizeof(int) * N);
    int*   rowptr  = (int*)  (base + off); off = align256(off + sizeof(int) * (N + 1));
    int*   cursor  = (int*)  (base + off); off = align256(off + sizeof(int) * N);
    int*   csr_src = (int*)  (base + off); off = align256(off + sizeof(int) * E);
    float* bufB    = (float*)(base + off); off = align256(off + sizeof(float) * (size_t)N * 64);
    float* bufA    = (float*)(base + off); off = align256(off + sizeof(float) * (size_t)N * 64);
    float* pooled  = (float*)(base + off); off = align256(off + sizeof(float) * G * 32);

    // ---- Build CSR by dst + dinv ----
    k_zero_int<<<cdiv(N, THREADS), THREADS, 0, stream>>>(counts, N);
    k_count<<<cdiv(E, THREADS), THREADS, 0, stream>>>(dstp, counts, E);
    k_scan<<<1, SCAN_T, 0, stream>>>(counts, rowptr, cursor, dinv, N);
    k_fill<<<cdiv(E, THREADS), THREADS, 0, stream>>>(srcp, dstp, cursor, csr_src, E);

    // ---- Layer 1: 128 -> 16, relu ----
    k_gemm_nodes<128, 16><<<cdiv(N, THREADS / 16), THREADS, 0, stream>>>(x, W1, dinv, bufB, N);
    k_pull<16, true><<<cdiv(N, THREADS / 16), THREADS, 0, stream>>>(rowptr, csr_src, dinv, bufB, b1, bufA, N);

    // ---- Layer 2: 16 -> 64, relu ----
    k_gemm_nodes<16, 64><<<cdiv(N, THREADS / 64), THREADS, 0, stream>>>(bufA, W2, dinv, bufB, N);
    k_pull<64, true><<<cdiv(N, THREADS / 64), THREADS, 0, stream>>>(rowptr, csr_src, dinv, bufB, b2, bufA, N);

    // ---- Layer 3: 64 -> 32, no relu ----
    k_gemm_nodes<64, 32><<<cdiv(N, THREADS / 32), THREADS, 0, stream>>>(bufA, W3, dinv, bufB, N);
    k_pull<32, false><<<cdiv(N, THREADS / 32), THREADS, 0, stream>>>(rowptr, csr_src, dinv, bufB, b3, bufA, N);

    // ---- Pool + head ----
    k_pool_mean<<<G, THREADS, 0, stream>>>(bufA, batch, N, pooled);
    k_head<<<G, 64, 0, stream>>>(pooled, Wa, ba, Wo, bo, (float*)d_out);
}

// Round 3
// 882.634 us; speedup vs baseline: 5.6187x; 1.4353x over previous
//
#include <hip/hip_runtime.h>
#include <hip/hip_bf16.h>
#include <math.h>

// ActorGNN R3: CSR pull + multi-block scan + padded atomic counters + layer-2
// aggregation re-associated to input width (16) + fused 16->64->32 node MLP.
// N=100000, E=3200000, G=64.

#define THREADS 256
#define PAD 16          // one counter per 64B line
#define CHUNK 1024      // counts per scan block

__global__ void k_zero4(int4* p, int n4) {
    int i = blockIdx.x * blockDim.x + threadIdx.x;
    if (i < n4) p[i] = make_int4(0, 0, 0, 0);
}

__global__ void k_count(const int* __restrict__ dst, int* __restrict__ counts_pad, int E) {
    int e = blockIdx.x * blockDim.x + threadIdx.x;
    if (e < E) atomicAdd(&counts_pad[(size_t)dst[e] * PAD], 1);
}

// Phase 1: per-block sums of CHUNK padded counts
__global__ void k_scan1(const int* __restrict__ counts_pad, int* __restrict__ bsum, int N) {
    __shared__ int red[THREADS];
    int t = threadIdx.x;
    int i0 = blockIdx.x * CHUNK + t * 4;
    int s = 0;
#pragma unroll
    for (int k = 0; k < 4; ++k) {
        int i = i0 + k;
        if (i < N) s += counts_pad[(size_t)i * PAD];
    }
    red[t] = s;
    __syncthreads();
    for (int off = THREADS / 2; off > 0; off >>= 1) {
        if (t < off) red[t] += red[t + off];
        __syncthreads();
    }
    if (t == 0) bsum[blockIdx.x] = red[0];
}

// Phase 2: single small block, exclusive scan of B block sums (B <= 128)
__global__ void k_scan2(int* __restrict__ bsum, int B) {
    __shared__ int sh[128];
    int t = threadIdx.x;
    int v = (t < B) ? bsum[t] : 0;
    sh[t] = v;
    __syncthreads();
    for (int off = 1; off < 128; off <<= 1) {
        int u = (t >= off) ? sh[t - off] : 0;
        __syncthreads();
        sh[t] += u;
        __syncthreads();
    }
    if (t < B) bsum[t] = sh[t] - v;  // exclusive
}

// Phase 3: local scan + offset; write rowptr, cursor (reuse counts_pad), dinv
__global__ void k_scan3(int* __restrict__ counts_pad, const int* __restrict__ bsum,
                        int* __restrict__ rowptr, float* __restrict__ dinv, int N) {
    __shared__ int sh[THREADS];
    int t = threadIdx.x;
    int i0 = blockIdx.x * CHUNK + t * 4;
    int c[4];
    int tsum = 0;
#pragma unroll
    for (int k = 0; k < 4; ++k) {
        int i = i0 + k;
        c[k] = (i < N) ? counts_pad[(size_t)i * PAD] : 0;
        tsum += c[k];
    }
    sh[t] = tsum;
    __syncthreads();
    for (int off = 1; off < THREADS; off <<= 1) {
        int u = (t >= off) ? sh[t - off] : 0;
        __syncthreads();
        sh[t] += u;
        __syncthreads();
    }
    int run = sh[t] - tsum + bsum[blockIdx.x];  // exclusive prefix
#pragma unroll
    for (int k = 0; k < 4; ++k) {
        int i = i0 + k;
        if (i < N) {
            rowptr[i] = run;
            counts_pad[(size_t)i * PAD] = run;  // becomes cursor for k_fill
            dinv[i] = (float)(1.0 / sqrt((double)(c[k] + 1)));
            run += c[k];
            if (i == N - 1) rowptr[N] = run;
        }
    }
}

__global__ void k_fill(const int* __restrict__ src, const int* __restrict__ dst,
                       int* __restrict__ cursor_pad, int* __restrict__ csr_src, int E) {
    int e = blockIdx.x * blockDim.x + threadIdx.x;
    if (e < E) {
        int d = dst[e];
        int pos = atomicAdd(&cursor_pad[(size_t)d * PAD], 1);
        csr_src[pos] = src[e];
    }
}

// Hs1[n][j] = (sum_k X[n][k] * W[k][j]) * dinv[n]   (K=128, J=16)
__global__ void k_gemm1(const float* __restrict__ X, const float* __restrict__ W,
                        const float* __restrict__ dinv, float* __restrict__ H, int N) {
    __shared__ float Ws[128 * 16];
    for (int i = threadIdx.x; i < 128 * 16; i += blockDim.x) Ws[i] = W[i];
    __syncthreads();
    int row = blockIdx.x * 16 + threadIdx.x / 16;
    int j = threadIdx.x % 16;
    if (row >= N) return;
    const float4* xr4 = (const float4*)(X + (size_t)row * 128);
    float acc = 0.0f;
#pragma unroll
    for (int k4 = 0; k4 < 32; ++k4) {
        float4 xv = xr4[k4];
        acc += xv.x * Ws[(k4 * 4 + 0) * 16 + j];
        acc += xv.y * Ws[(k4 * 4 + 1) * 16 + j];
        acc += xv.z * Ws[(k4 * 4 + 2) * 16 + j];
        acc += xv.w * Ws[(k4 * 4 + 3) * 16 + j];
    }
    H[(size_t)row * 16 + j] = acc * dinv[row];
}

// Pull: t = dinv[n]*(sum_{e->n} Hs[src][f] + Hs[n][f])
// MODE 0: out = t + b[f]                (final layer, pre-pool)
// MODE 1: out = relu(t + b[f])*dinv[n]  (L1 out, pre-scaled for next pull)
// MODE 2: out = t                       (L2 pre-GEMM aggregate)
template<int F, int MODE>
__global__ void k_pull(const int* __restrict__ rowptr, const int* __restrict__ csr_src,
                       const float* __restrict__ dinv, const float* __restrict__ Hs,
                       const float* __restrict__ b, float* __restrict__ out, int N) {
    const int NODES = THREADS / F;
    int node = blockIdx.x * NODES + threadIdx.x / F;
    int f = threadIdx.x % F;
    if (node >= N) return;
    int beg = rowptr[node];
    int end = rowptr[node + 1];
    float acc = 0.0f;
    int i = beg;
    int sNext = (i < end) ? csr_src[i] : 0;
    for (; i < end; ++i) {
        int s = sNext;
        if (i + 1 < end) sNext = csr_src[i + 1];
        acc += Hs[(size_t)s * F + f];
    }
    float di = dinv[node];
    float t = di * (acc + Hs[(size_t)node * F + f]);
    float v;
    if (MODE == 0) v = t + b[f];
    else if (MODE == 1) v = fmaxf(t + b[f], 0.0f) * di;
    else v = t;
    out[(size_t)node * F + f] = v;
}

// Fused per-node MLP: Hs3[n] = (relu(P2[n] @ W2 + b2) @ W3) * dinv[n]
// 4 nodes per 256-thread block; W2[16x64], W3[64x32], b2 in LDS.
__global__ void k_mlp(const float* __restrict__ P2, const float* __restrict__ W2,
                      const float* __restrict__ b2, const float* __restrict__ W3,
                      const float* __restrict__ dinv, float* __restrict__ Hs3, int N) {
    __shared__ float W2s[16 * 64];
    __shared__ float W3s[64 * 32];
    __shared__ float b2s[64];
    __shared__ float ps[4][16];
    __shared__ float as[4][64];
    int t = threadIdx.x;
    for (int i = t; i < 16 * 64; i += THREADS) W2s[i] = W2[i];
    for (int i = t; i < 64 * 32; i += THREADS) W3s[i] = W3[i];
    if (t < 64) b2s[t] = b2[t];
    int ln = t / 64;   // local node 0..3
    int j = t % 64;
    int node = blockIdx.x * 4 + ln;
    __syncthreads();
    if (node < N) {
        if (j < 16) ps[ln][j] = P2[(size_t)node * 16 + j];
    }
    __syncthreads();
    if (node < N) {
        float a = b2s[j];
#pragma unroll
        for (int k = 0; k < 16; ++k) a += ps[ln][k] * W2s[k * 64 + j];
        as[ln][j] = fmaxf(a, 0.0f);
    }
    __syncthreads();
    if (node < N && j < 32) {
        float o = 0.0f;
#pragma unroll
        for (int k = 0; k < 64; ++k) o += as[ln][k] * W3s[k * 32 + j];
        Hs3[(size_t)node * 32 + j] = o * dinv[node];
    }
}

// batch sorted: block g binary-searches its node range, mean over 32 features
__global__ void k_pool_mean(const float* __restrict__ h, const int* __restrict__ batch,
                            int N, float* __restrict__ pooled) {
    int g = blockIdx.x;
    int lo = 0, hi = N;
    while (lo < hi) { int m = (lo + hi) >> 1; if (batch[m] < g) lo = m + 1; else hi = m; }
    int start = lo;
    lo = start; hi = N;
    while (lo < hi) { int m = (lo + hi) >> 1; if (batch[m] < g + 1) lo = m + 1; else hi = m; }
    int end = lo;

    __shared__ float partial[THREADS];
    int f = threadIdx.x % 32;
    int grp = threadIdx.x / 32;
    float acc = 0.0f;
    for (int n = start + grp; n < end; n += 8) acc += h[(size_t)n * 32 + f];
    partial[threadIdx.x] = acc;
    __syncthreads();
    if (threadIdx.x < 32) {
        float s = 0.0f;
#pragma unroll
        for (int tt = 0; tt < 8; ++tt) s += partial[tt * 32 + f];
        int cnt = end - start;
        pooled[g * 32 + f] = s / (float)(cnt > 0 ? cnt : 1);
    }
}

// a = relu(pooled @ Wa + ba) [G,64]; out = tanh(a @ Wo + bo) [G,32]
__global__ void k_head(const float* __restrict__ pooled, const float* __restrict__ Wa,
                       const float* __restrict__ ba, const float* __restrict__ Wo,
                       const float* __restrict__ bo, float* __restrict__ out) {
    int g = blockIdx.x;
    int j = threadIdx.x;  // 64 threads
    __shared__ float p[32];
    __shared__ float a[64];
    if (j < 32) p[j] = pooled[g * 32 + j];
    __syncthreads();
    float acc = ba[j];
#pragma unroll
    for (int k = 0; k < 32; ++k) acc += p[k] * Wa[k * 64 + j];
    a[j] = fmaxf(acc, 0.0f);
    __syncthreads();
    if (j < 32) {
        float acc2 = bo[j];
#pragma unroll
        for (int k = 0; k < 64; ++k) acc2 += a[k] * Wo[k * 32 + j];
        out[g * 32 + j] = tanhf(acc2);
    }
}

static inline int cdiv(long long a, int b) { return (int)((a + b - 1) / b); }
static inline size_t align256(size_t x) { return (x + 255) & ~(size_t)255; }

extern "C" void kernel_launch(void* const* d_in, const int* in_sizes, int n_in,
                              void* d_out, int out_size, void* d_ws, size_t ws_size,
                              hipStream_t stream) {
    const float* x     = (const float*)d_in[0];   // [N,128]
    const int*   edge  = (const int*)d_in[1];     // [2,E]: src row, dst row
    const int*   batch = (const int*)d_in[2];     // [N], sorted
    const float* W1 = (const float*)d_in[3];  const float* b1 = (const float*)d_in[4];
    const float* W2 = (const float*)d_in[5];  const float* b2 = (const float*)d_in[6];
    const float* W3 = (const float*)d_in[7];  const float* b3 = (const float*)d_in[8];
    const float* Wa = (const float*)d_in[9];  const float* ba = (const float*)d_in[10];
    const float* Wo = (const float*)d_in[11]; const float* bo = (const float*)d_in[12];

    const int E = in_sizes[1] / 2;
    const int N = in_sizes[2];
    const int G = 64;
    const int B = cdiv(N, CHUNK);  // scan blocks (98 for N=100000)

    const int* srcp = edge;
    const int* dstp = edge + E;

    // Workspace
    char* base = (char*)d_ws;
    size_t off = 0;
    float* dinv    = (float*)(base + off); off = align256(off + sizeof(float) * N);
    int*   cpad    = (int*)  (base + off); off = align256(off + sizeof(int) * (size_t)N * PAD);
    int*   bsum    = (int*)  (base + off); off = align256(off + sizeof(int) * 128);
    int*   rowptr  = (int*)  (base + off); off = align256(off + sizeof(int) * (N + 1));
    int*   csr_src = (int*)  (base + off); off = align256(off + sizeof(int) * E);
    float* bufB    = (float*)(base + off); off = align256(off + sizeof(float) * (size_t)N * 32);
    float* bufA    = (float*)(base + off); off = align256(off + sizeof(float) * (size_t)N * 32);
    float* pooled  = (float*)(base + off); off = align256(off + sizeof(float) * G * 32);

    // ---- CSR build ----
    int n4 = (N * PAD) / 4;
    k_zero4<<<cdiv(n4, THREADS), THREADS, 0, stream>>>((int4*)cpad, n4);
    k_count<<<cdiv(E, THREADS), THREADS, 0, stream>>>(dstp, cpad, E);
    k_scan1<<<B, THREADS, 0, stream>>>(cpad, bsum, N);
    k_scan2<<<1, 128, 0, stream>>>(bsum, B);
    k_scan3<<<B, THREADS, 0, stream>>>(cpad, bsum, rowptr, dinv, N);
    k_fill<<<cdiv(E, THREADS), THREADS, 0, stream>>>(srcp, dstp, cpad, csr_src, E);

    // ---- Layer 1: Hs1=(x@W1)*dinv ; pull16 -> Hs2=relu(.+b1)*dinv ----
    k_gemm1<<<cdiv(N, 16), THREADS, 0, stream>>>(x, W1, dinv, bufB, N);
    k_pull<16, 1><<<cdiv(N, 16), THREADS, 0, stream>>>(rowptr, csr_src, dinv, bufB, b1, bufA, N);

    // ---- Layer 2 aggregate in input width: P2 = pull16(Hs2) ----
    k_pull<16, 2><<<cdiv(N, 16), THREADS, 0, stream>>>(rowptr, csr_src, dinv, bufA, b1 /*unused*/, bufB, N);

    // ---- Fused node MLP: Hs3 = (relu(P2@W2+b2)@W3)*dinv ----
    k_mlp<<<cdiv(N, 4), THREADS, 0, stream>>>(bufB, W2, b2, W3, dinv, bufA, N);

    // ---- Layer 3 aggregate: h3 = pull32(Hs3) + b3 ----
    k_pull<32, 0><<<cdiv(N, 8), THREADS, 0, stream>>>(rowptr, csr_src, dinv, bufA, b3, bufB, N);

    // ---- Pool + head ----
    k_pool_mean<<<G, THREADS, 0, stream>>>(bufB, batch, N, pooled);
    k_head<<<G, 64, 0, stream>>>(pooled, Wa, ba, Wo, bo, (float*)d_out);
}

// Round 4
// 571.881 us; speedup vs baseline: 8.6718x; 1.5434x over previous
//
#include <hip/hip_runtime.h>
#include <hip/hip_bf16.h>
#include <math.h>

// ActorGNN R4: CSR build via two-level LDS-binned counting sort (no per-edge
// global atomics), then pull-based aggregation (R3 algebra: layer-2 aggregated
// at input width 16, fused 16->64->32 node MLP).
// N=100000, E=3200000, G=64. Buckets: dst>>8 -> NB=ceil(N/256)=391.

#define THREADS 256
#define BSH 8                 // bucket shift
#define MAXNB 512             // LDS histogram capacity (N <= 131072)
#define CH_E 8192             // edges per block in binning passes

__global__ void k_zero_int(int* p, int n) {
    int i = blockIdx.x * blockDim.x + threadIdx.x;
    if (i < n) p[i] = 0;
}

// Pass 1: coarse histogram of dst buckets (LDS), flush with ~NB atomics/block
__global__ void k_bincount(const int* __restrict__ dst, int* __restrict__ bucket_cnt,
                           int E, int NB) {
    __shared__ int hist[MAXNB];
    int t = threadIdx.x;
    for (int h = t; h < NB; h += THREADS) hist[h] = 0;
    __syncthreads();
    int e0 = blockIdx.x * CH_E;
    int e1 = min(E, e0 + CH_E);
    for (int e = e0 + t; e < e1; e += THREADS)
        atomicAdd(&hist[dst[e] >> BSH], 1);
    __syncthreads();
    for (int h = t; h < NB; h += THREADS)
        if (hist[h]) atomicAdd(&bucket_cnt[h], hist[h]);
}

// Pass 2: single block scans NB bucket counts -> base & cursor; rowptr[N]=E
__global__ void k_bucket_scan(const int* __restrict__ bucket_cnt, int* __restrict__ bucket_base,
                              int* __restrict__ bucket_cursor, int* __restrict__ rowptr,
                              int NB, int N, int E) {
    __shared__ int sh[MAXNB];
    int t = threadIdx.x;  // 512 threads
    int v = (t < NB) ? bucket_cnt[t] : 0;
    sh[t] = v;
    __syncthreads();
    for (int off = 1; off < MAXNB; off <<= 1) {
        int u = (t >= off) ? sh[t - off] : 0;
        __syncthreads();
        sh[t] += u;
        __syncthreads();
    }
    if (t < NB) {
        int excl = sh[t] - v;
        bucket_base[t] = excl;
        bucket_cursor[t] = excl;
    }
    if (t == 0) {
        bucket_base[NB] = E;
        rowptr[N] = E;
    }
}

// Pass 3: scatter packed (src<<8 | dst&255) into bucket regions.
// One reservation atomic per (block,bucket); payload written contiguously.
__global__ void k_binscatter(const int* __restrict__ src, const int* __restrict__ dst,
                             int* __restrict__ bucket_cursor, unsigned int* __restrict__ bedges,
                             int E, int NB) {
    __shared__ int hist[MAXNB];
    __shared__ int lbase[MAXNB];
    int t = threadIdx.x;
    for (int h = t; h < NB; h += THREADS) hist[h] = 0;
    __syncthreads();
    int e0 = blockIdx.x * CH_E;
    int e1 = min(E, e0 + CH_E);
    for (int e = e0 + t; e < e1; e += THREADS)
        atomicAdd(&hist[dst[e] >> BSH], 1);
    __syncthreads();
    for (int h = t; h < NB; h += THREADS) {
        int c = hist[h];
        if (c) lbase[h] = atomicAdd(&bucket_cursor[h], c);
        hist[h] = 0;  // becomes local cursor
    }
    __syncthreads();
    for (int e = e0 + t; e < e1; e += THREADS) {
        int d = dst[e];
        int h = d >> BSH;
        int lp = atomicAdd(&hist[h], 1);
        bedges[lbase[h] + lp] = ((unsigned int)src[e] << BSH) | (unsigned int)(d & ((1 << BSH) - 1));
    }
}

// Pass 4: block b = bucket b (<=256 nodes). LDS per-node histogram -> rowptr,
// dinv; LDS cursors place srcs into csr_src. Replaces k_count + k_fill.
__global__ void k_bucket_csr(const unsigned int* __restrict__ bedges,
                             const int* __restrict__ bucket_base,
                             int* __restrict__ rowptr, float* __restrict__ dinv,
                             int* __restrict__ csr_src, int N) {
    __shared__ int hist[THREADS];
    __shared__ int sc[THREADS];
    __shared__ int cur[THREADS];
    int t = threadIdx.x;
    int b = blockIdx.x;
    int base = bucket_base[b];
    int end = bucket_base[b + 1];
    hist[t] = 0;
    __syncthreads();
    for (int i = base + t; i < end; i += THREADS)
        atomicAdd(&hist[bedges[i] & (THREADS - 1)], 1);
    __syncthreads();
    int c = hist[t];
    sc[t] = c;
    __syncthreads();
    for (int off = 1; off < THREADS; off <<= 1) {
        int u = (t >= off) ? sc[t - off] : 0;
        __syncthreads();
        sc[t] += u;
        __syncthreads();
    }
    int excl = sc[t] - c;
    int node = (b << BSH) + t;
    if (node < N) {
        rowptr[node] = base + excl;
        dinv[node] = (float)(1.0 / sqrt((double)(c + 1)));
    }
    cur[t] = excl;
    __syncthreads();
    for (int i = base + t; i < end; i += THREADS) {
        unsigned int u = bedges[i];
        int ln = (int)(u & (THREADS - 1));
        int p = atomicAdd(&cur[ln], 1);
        csr_src[base + p] = (int)(u >> BSH);
    }
}

// Hs1[n][j] = (sum_k X[n][k] * W[k][j]) * dinv[n]   (K=128, J=16)
__global__ void k_gemm1(const float* __restrict__ X, const float* __restrict__ W,
                        const float* __restrict__ dinv, float* __restrict__ H, int N) {
    __shared__ float Ws[128 * 16];
    for (int i = threadIdx.x; i < 128 * 16; i += blockDim.x) Ws[i] = W[i];
    __syncthreads();
    int row = blockIdx.x * 16 + threadIdx.x / 16;
    int j = threadIdx.x % 16;
    if (row >= N) return;
    const float4* xr4 = (const float4*)(X + (size_t)row * 128);
    float acc = 0.0f;
#pragma unroll
    for (int k4 = 0; k4 < 32; ++k4) {
        float4 xv = xr4[k4];
        acc += xv.x * Ws[(k4 * 4 + 0) * 16 + j];
        acc += xv.y * Ws[(k4 * 4 + 1) * 16 + j];
        acc += xv.z * Ws[(k4 * 4 + 2) * 16 + j];
        acc += xv.w * Ws[(k4 * 4 + 3) * 16 + j];
    }
    H[(size_t)row * 16 + j] = acc * dinv[row];
}

// Pull: t = dinv[n]*(sum_{e->n} Hs[src][f] + Hs[n][f])
// MODE 0: out = t + b[f]                (final layer, pre-pool)
// MODE 1: out = relu(t + b[f])*dinv[n]  (L1 out, pre-scaled for next pull)
// MODE 2: out = t                       (L2 pre-GEMM aggregate)
template<int F, int MODE>
__global__ void k_pull(const int* __restrict__ rowptr, const int* __restrict__ csr_src,
                       const float* __restrict__ dinv, const float* __restrict__ Hs,
                       const float* __restrict__ b, float* __restrict__ out, int N) {
    const int NODES = THREADS / F;
    int node = blockIdx.x * NODES + threadIdx.x / F;
    int f = threadIdx.x % F;
    if (node >= N) return;
    int beg = rowptr[node];
    int end = rowptr[node + 1];
    float acc = 0.0f;
    int i = beg;
    int sNext = (i < end) ? csr_src[i] : 0;
    for (; i < end; ++i) {
        int s = sNext;
        if (i + 1 < end) sNext = csr_src[i + 1];
        acc += Hs[(size_t)s * F + f];
    }
    float di = dinv[node];
    float t = di * (acc + Hs[(size_t)node * F + f]);
    float v;
    if (MODE == 0) v = t + b[f];
    else if (MODE == 1) v = fmaxf(t + b[f], 0.0f) * di;
    else v = t;
    out[(size_t)node * F + f] = v;
}

// Fused per-node MLP: Hs3[n] = (relu(P2[n] @ W2 + b2) @ W3) * dinv[n]
__global__ void k_mlp(const float* __restrict__ P2, const float* __restrict__ W2,
                      const float* __restrict__ b2, const float* __restrict__ W3,
                      const float* __restrict__ dinv, float* __restrict__ Hs3, int N) {
    __shared__ float W2s[16 * 64];
    __shared__ float W3s[64 * 32];
    __shared__ float b2s[64];
    __shared__ float ps[4][16];
    __shared__ float as[4][64];
    int t = threadIdx.x;
    for (int i = t; i < 16 * 64; i += THREADS) W2s[i] = W2[i];
    for (int i = t; i < 64 * 32; i += THREADS) W3s[i] = W3[i];
    if (t < 64) b2s[t] = b2[t];
    int ln = t / 64;
    int j = t % 64;
    int node = blockIdx.x * 4 + ln;
    __syncthreads();
    if (node < N && j < 16) ps[ln][j] = P2[(size_t)node * 16 + j];
    __syncthreads();
    if (node < N) {
        float a = b2s[j];
#pragma unroll
        for (int k = 0; k < 16; ++k) a += ps[ln][k] * W2s[k * 64 + j];
        as[ln][j] = fmaxf(a, 0.0f);
    }
    __syncthreads();
    if (node < N && j < 32) {
        float o = 0.0f;
#pragma unroll
        for (int k = 0; k < 64; ++k) o += as[ln][k] * W3s[k * 32 + j];
        Hs3[(size_t)node * 32 + j] = o * dinv[node];
    }
}

// batch sorted: block g binary-searches its node range, mean over 32 features
__global__ void k_pool_mean(const float* __restrict__ h, const int* __restrict__ batch,
                            int N, float* __restrict__ pooled) {
    int g = blockIdx.x;
    int lo = 0, hi = N;
    while (lo < hi) { int m = (lo + hi) >> 1; if (batch[m] < g) lo = m + 1; else hi = m; }
    int start = lo;
    lo = start; hi = N;
    while (lo < hi) { int m = (lo + hi) >> 1; if (batch[m] < g + 1) lo = m + 1; else hi = m; }
    int end = lo;

    __shared__ float partial[THREADS];
    int f = threadIdx.x % 32;
    int grp = threadIdx.x / 32;
    float acc = 0.0f;
    for (int n = start + grp; n < end; n += 8) acc += h[(size_t)n * 32 + f];
    partial[threadIdx.x] = acc;
    __syncthreads();
    if (threadIdx.x < 32) {
        float s = 0.0f;
#pragma unroll
        for (int tt = 0; tt < 8; ++tt) s += partial[tt * 32 + f];
        int cnt = end - start;
        pooled[g * 32 + f] = s / (float)(cnt > 0 ? cnt : 1);
    }
}

// a = relu(pooled @ Wa + ba) [G,64]; out = tanh(a @ Wo + bo) [G,32]
__global__ void k_head(const float* __restrict__ pooled, const float* __restrict__ Wa,
                       const float* __restrict__ ba, const float* __restrict__ Wo,
                       const float* __restrict__ bo, float* __restrict__ out) {
    int g = blockIdx.x;
    int j = threadIdx.x;  // 64 threads
    __shared__ float p[32];
    __shared__ float a[64];
    if (j < 32) p[j] = pooled[g * 32 + j];
    __syncthreads();
    float acc = ba[j];
#pragma unroll
    for (int k = 0; k < 32; ++k) acc += p[k] * Wa[k * 64 + j];
    a[j] = fmaxf(acc, 0.0f);
    __syncthreads();
    if (j < 32) {
        float acc2 = bo[j];
#pragma unroll
        for (int k = 0; k < 64; ++k) acc2 += a[k] * Wo[k * 32 + j];
        out[g * 32 + j] = tanhf(acc2);
    }
}

static inline int cdiv(long long a, int b) { return (int)((a + b - 1) / b); }
static inline size_t align256(size_t x) { return (x + 255) & ~(size_t)255; }

extern "C" void kernel_launch(void* const* d_in, const int* in_sizes, int n_in,
                              void* d_out, int out_size, void* d_ws, size_t ws_size,
                              hipStream_t stream) {
    const float* x     = (const float*)d_in[0];   // [N,128]
    const int*   edge  = (const int*)d_in[1];     // [2,E]: src row, dst row
    const int*   batch = (const int*)d_in[2];     // [N], sorted
    const float* W1 = (const float*)d_in[3];  const float* b1 = (const float*)d_in[4];
    const float* W2 = (const float*)d_in[5];  const float* b2 = (const float*)d_in[6];
    const float* W3 = (const float*)d_in[7];  const float* b3 = (const float*)d_in[8];
    const float* Wa = (const float*)d_in[9];  const float* ba = (const float*)d_in[10];
    const float* Wo = (const float*)d_in[11]; const float* bo = (const float*)d_in[12];

    const int E = in_sizes[1] / 2;
    const int N = in_sizes[2];
    const int G = 64;
    const int NB = cdiv(N, 1 << BSH);  // 391 for N=100000

    const int* srcp = edge;
    const int* dstp = edge + E;

    // Workspace
    char* base = (char*)d_ws;
    size_t off = 0;
    float* dinv     = (float*)(base + off); off = align256(off + sizeof(float) * N);
    int*   bcnt     = (int*)  (base + off); off = align256(off + sizeof(int) * (NB + 1));
    int*   bbase    = (int*)  (base + off); off = align256(off + sizeof(int) * (NB + 1));
    int*   bcur     = (int*)  (base + off); off = align256(off + sizeof(int) * (NB + 1));
    unsigned int* bedges = (unsigned int*)(base + off); off = align256(off + sizeof(int) * E);
    int*   rowptr   = (int*)  (base + off); off = align256(off + sizeof(int) * (N + 1));
    int*   csr_src  = (int*)  (base + off); off = align256(off + sizeof(int) * E);
    float* bufB     = (float*)(base + off); off = align256(off + sizeof(float) * (size_t)N * 32);
    float* bufA     = (float*)(base + off); off = align256(off + sizeof(float) * (size_t)N * 32);
    float* pooled   = (float*)(base + off); off = align256(off + sizeof(float) * G * 32);

    // ---- CSR build (binned counting sort, no per-edge global atomics) ----
    k_zero_int<<<cdiv(NB + 1, THREADS), THREADS, 0, stream>>>(bcnt, NB + 1);
    k_bincount<<<cdiv(E, CH_E), THREADS, 0, stream>>>(dstp, bcnt, E, NB);
    k_bucket_scan<<<1, MAXNB, 0, stream>>>(bcnt, bbase, bcur, rowptr, NB, N, E);
    k_binscatter<<<cdiv(E, CH_E), THREADS, 0, stream>>>(srcp, dstp, bcur, bedges, E, NB);
    k_bucket_csr<<<NB, THREADS, 0, stream>>>(bedges, bbase, rowptr, dinv, csr_src, N);

    // ---- Layer 1: Hs1=(x@W1)*dinv ; pull16 -> Hs2=relu(.+b1)*dinv ----
    k_gemm1<<<cdiv(N, 16), THREADS, 0, stream>>>(x, W1, dinv, bufB, N);
    k_pull<16, 1><<<cdiv(N, 16), THREADS, 0, stream>>>(rowptr, csr_src, dinv, bufB, b1, bufA, N);

    // ---- Layer 2 aggregate at input width: P2 = pull16(Hs2) ----
    k_pull<16, 2><<<cdiv(N, 16), THREADS, 0, stream>>>(rowptr, csr_src, dinv, bufA, b1 /*unused*/, bufB, N);

    // ---- Fused node MLP: Hs3 = (relu(P2@W2+b2)@W3)*dinv ----
    k_mlp<<<cdiv(N, 4), THREADS, 0, stream>>>(bufB, W2, b2, W3, dinv, bufA, N);

    // ---- Layer 3 aggregate: h3 = pull32(Hs3) + b3 ----
    k_pull<32, 0><<<cdiv(N, 8), THREADS, 0, stream>>>(rowptr, csr_src, dinv, bufA, b3, bufB, N);

    // ---- Pool + head ----
    k_pool_mean<<<G, THREADS, 0, stream>>>(bufB, batch, N, pooled);
    k_head<<<G, 64, 0, stream>>>(pooled, Wa, ba, Wo, bo, (float*)d_out);
}

// Round 5
// 446.035 us; speedup vs baseline: 11.1185x; 1.2821x over previous
//
#include <hip/hip_runtime.h>
#include <hip/hip_bf16.h>
#include <math.h>

// ActorGNN R5: R4 structure + bf16 gather tables + MLP-4 unrolled vector pulls.
// N=100000, E=3200000, G=64. Layers 128->16->64->32, pool, head 32->64->32.

#define THREADS 256
#define BSH 8                 // bucket shift
#define MAXNB 512             // LDS histogram capacity (N <= 131072)
#define CH_E 8192             // edges per block in binning passes

// ---- bf16 helpers (tables stored as unsigned short) ----
__device__ inline unsigned short f2bf(float f) {
    unsigned int u = __float_as_uint(f);
    unsigned int r = (u + 0x7fffu + ((u >> 16) & 1u)) >> 16;  // RNE
    return (unsigned short)r;
}
__device__ inline unsigned int pk2bf(float a, float b) {
    return (unsigned int)f2bf(a) | ((unsigned int)f2bf(b) << 16);
}
__device__ inline float4 ldbf4(const unsigned short* p) {
    uint2 u = *(const uint2*)p;  // 4 bf16 = 8B
    float4 r;
    r.x = __uint_as_float(u.x << 16);
    r.y = __uint_as_float(u.x & 0xffff0000u);
    r.z = __uint_as_float(u.y << 16);
    r.w = __uint_as_float(u.y & 0xffff0000u);
    return r;
}

__global__ void k_zero_int(int* p, int n) {
    int i = blockIdx.x * blockDim.x + threadIdx.x;
    if (i < n) p[i] = 0;
}

// Pass 1: coarse histogram of dst buckets (LDS), flush with ~NB atomics/block
__global__ void k_bincount(const int* __restrict__ dst, int* __restrict__ bucket_cnt,
                           int E, int NB) {
    __shared__ int hist[MAXNB];
    int t = threadIdx.x;
    for (int h = t; h < NB; h += THREADS) hist[h] = 0;
    __syncthreads();
    int e0 = blockIdx.x * CH_E;
    int e1 = min(E, e0 + CH_E);
    for (int e = e0 + t; e < e1; e += THREADS)
        atomicAdd(&hist[dst[e] >> BSH], 1);
    __syncthreads();
    for (int h = t; h < NB; h += THREADS)
        if (hist[h]) atomicAdd(&bucket_cnt[h], hist[h]);
}

// Pass 2: single block scans NB bucket counts -> base & cursor; rowptr[N]=E
__global__ void k_bucket_scan(const int* __restrict__ bucket_cnt, int* __restrict__ bucket_base,
                              int* __restrict__ bucket_cursor, int* __restrict__ rowptr,
                              int NB, int N, int E) {
    __shared__ int sh[MAXNB];
    int t = threadIdx.x;  // 512 threads
    int v = (t < NB) ? bucket_cnt[t] : 0;
    sh[t] = v;
    __syncthreads();
    for (int off = 1; off < MAXNB; off <<= 1) {
        int u = (t >= off) ? sh[t - off] : 0;
        __syncthreads();
        sh[t] += u;
        __syncthreads();
    }
    if (t < NB) {
        int excl = sh[t] - v;
        bucket_base[t] = excl;
        bucket_cursor[t] = excl;
    }
    if (t == 0) {
        bucket_base[NB] = E;
        rowptr[N] = E;
    }
}

// Pass 3: scatter packed (src<<8 | dst&255) into bucket regions.
__global__ void k_binscatter(const int* __restrict__ src, const int* __restrict__ dst,
                             int* __restrict__ bucket_cursor, unsigned int* __restrict__ bedges,
                             int E, int NB) {
    __shared__ int hist[MAXNB];
    __shared__ int lbase[MAXNB];
    int t = threadIdx.x;
    for (int h = t; h < NB; h += THREADS) hist[h] = 0;
    __syncthreads();
    int e0 = blockIdx.x * CH_E;
    int e1 = min(E, e0 + CH_E);
    for (int e = e0 + t; e < e1; e += THREADS)
        atomicAdd(&hist[dst[e] >> BSH], 1);
    __syncthreads();
    for (int h = t; h < NB; h += THREADS) {
        int c = hist[h];
        if (c) lbase[h] = atomicAdd(&bucket_cursor[h], c);
        hist[h] = 0;  // becomes local cursor
    }
    __syncthreads();
    for (int e = e0 + t; e < e1; e += THREADS) {
        int d = dst[e];
        int h = d >> BSH;
        int lp = atomicAdd(&hist[h], 1);
        bedges[lbase[h] + lp] = ((unsigned int)src[e] << BSH) | (unsigned int)(d & ((1 << BSH) - 1));
    }
}

// Pass 4: block = bucket (<=256 nodes): LDS histogram -> rowptr, dinv; place srcs.
__global__ void k_bucket_csr(const unsigned int* __restrict__ bedges,
                             const int* __restrict__ bucket_base,
                             int* __restrict__ rowptr, float* __restrict__ dinv,
                             int* __restrict__ csr_src, int N) {
    __shared__ int hist[THREADS];
    __shared__ int sc[THREADS];
    __shared__ int cur[THREADS];
    int t = threadIdx.x;
    int b = blockIdx.x;
    int base = bucket_base[b];
    int end = bucket_base[b + 1];
    hist[t] = 0;
    __syncthreads();
    for (int i = base + t; i < end; i += THREADS)
        atomicAdd(&hist[bedges[i] & (THREADS - 1)], 1);
    __syncthreads();
    int c = hist[t];
    sc[t] = c;
    __syncthreads();
    for (int off = 1; off < THREADS; off <<= 1) {
        int u = (t >= off) ? sc[t - off] : 0;
        __syncthreads();
        sc[t] += u;
        __syncthreads();
    }
    int excl = sc[t] - c;
    int node = (b << BSH) + t;
    if (node < N) {
        rowptr[node] = base + excl;
        dinv[node] = (float)(1.0 / sqrt((double)(c + 1)));
    }
    cur[t] = excl;
    __syncthreads();
    for (int i = base + t; i < end; i += THREADS) {
        unsigned int u = bedges[i];
        int ln = (int)(u & (THREADS - 1));
        int p = atomicAdd(&cur[ln], 1);
        csr_src[base + p] = (int)(u >> BSH);
    }
}

// Hb1[n][j] = bf16( (sum_k X[n][k] * W[k][j]) * dinv[n] )   (K=128, J=16)
__global__ void k_gemm1(const float* __restrict__ X, const float* __restrict__ W,
                        const float* __restrict__ dinv, unsigned short* __restrict__ H, int N) {
    __shared__ float Ws[128 * 16];
    for (int i = threadIdx.x; i < 128 * 16; i += blockDim.x) Ws[i] = W[i];
    __syncthreads();
    int row = blockIdx.x * 16 + threadIdx.x / 16;
    int j = threadIdx.x % 16;
    if (row >= N) return;
    const float4* xr4 = (const float4*)(X + (size_t)row * 128);
    float acc = 0.0f;
#pragma unroll
    for (int k4 = 0; k4 < 32; ++k4) {
        float4 xv = xr4[k4];
        acc += xv.x * Ws[(k4 * 4 + 0) * 16 + j];
        acc += xv.y * Ws[(k4 * 4 + 1) * 16 + j];
        acc += xv.z * Ws[(k4 * 4 + 2) * 16 + j];
        acc += xv.w * Ws[(k4 * 4 + 3) * 16 + j];
    }
    H[(size_t)row * 16 + j] = f2bf(acc * dinv[row]);
}

// Pull from bf16 table: t = dinv[n]*(sum_{e->n} Hb[src] + Hb[n]); 4 features/lane.
// MODE 0: fp32 out = t + b          (final layer, pre-pool)
// MODE 1: bf16 out = relu(t+b)*dinv (L1 out, pre-scaled for next pull)
// MODE 2: fp32 out = t              (L2 pre-GEMM aggregate)
template<int F, int MODE>
__global__ void k_pull(const int* __restrict__ rowptr, const int* __restrict__ csr_src,
                       const float* __restrict__ dinv, const unsigned short* __restrict__ Hb,
                       const float* __restrict__ bias, void* __restrict__ outp, int N) {
    const int LPN = F / 4;             // lanes per node
    const int NPB = THREADS / LPN;     // nodes per block
    int node = blockIdx.x * NPB + threadIdx.x / LPN;
    int fq = threadIdx.x % LPN;        // feature quad
    if (node >= N) return;
    int beg = rowptr[node], end = rowptr[node + 1];
    const size_t off = (size_t)4 * fq;
    float4 acc = make_float4(0.f, 0.f, 0.f, 0.f);
    int i = beg;
    for (; i + 4 <= end; i += 4) {
        int s0 = csr_src[i + 0];
        int s1 = csr_src[i + 1];
        int s2 = csr_src[i + 2];
        int s3 = csr_src[i + 3];
        float4 g0 = ldbf4(Hb + (size_t)s0 * F + off);
        float4 g1 = ldbf4(Hb + (size_t)s1 * F + off);
        float4 g2 = ldbf4(Hb + (size_t)s2 * F + off);
        float4 g3 = ldbf4(Hb + (size_t)s3 * F + off);
        acc.x += (g0.x + g1.x) + (g2.x + g3.x);
        acc.y += (g0.y + g1.y) + (g2.y + g3.y);
        acc.z += (g0.z + g1.z) + (g2.z + g3.z);
        acc.w += (g0.w + g1.w) + (g2.w + g3.w);
    }
    for (; i < end; ++i) {
        int s = csr_src[i];
        float4 g = ldbf4(Hb + (size_t)s * F + off);
        acc.x += g.x; acc.y += g.y; acc.z += g.z; acc.w += g.w;
    }
    float4 self = ldbf4(Hb + (size_t)node * F + off);
    float di = dinv[node];
    float4 t;
    t.x = di * (acc.x + self.x);
    t.y = di * (acc.y + self.y);
    t.z = di * (acc.z + self.z);
    t.w = di * (acc.w + self.w);
    if (MODE == 0) {
        float4 o;
        o.x = t.x + bias[4 * fq + 0];
        o.y = t.y + bias[4 * fq + 1];
        o.z = t.z + bias[4 * fq + 2];
        o.w = t.w + bias[4 * fq + 3];
        *(float4*)((float*)outp + (size_t)node * F + off) = o;
    } else if (MODE == 1) {
        float4 v;
        v.x = fmaxf(t.x + bias[4 * fq + 0], 0.f) * di;
        v.y = fmaxf(t.y + bias[4 * fq + 1], 0.f) * di;
        v.z = fmaxf(t.z + bias[4 * fq + 2], 0.f) * di;
        v.w = fmaxf(t.w + bias[4 * fq + 3], 0.f) * di;
        uint2 st;
        st.x = pk2bf(v.x, v.y);
        st.y = pk2bf(v.z, v.w);
        *(uint2*)((unsigned short*)outp + (size_t)node * F + off) = st;
    } else {
        *(float4*)((float*)outp + (size_t)node * F + off) = t;
    }
}

// Fused per-node MLP: Hb3[n] = bf16( (relu(P2[n] @ W2 + b2) @ W3) * dinv[n] )
__global__ void k_mlp(const float* __restrict__ P2, const float* __restrict__ W2,
                      const float* __restrict__ b2, const float* __restrict__ W3,
                      const float* __restrict__ dinv, unsigned short* __restrict__ Hb3, int N) {
    __shared__ float W2s[16 * 64];
    __shared__ float W3s[64 * 32];
    __shared__ float b2s[64];
    __shared__ float ps[4][16];
    __shared__ float as[4][64];
    int t = threadIdx.x;
    for (int i = t; i < 16 * 64; i += THREADS) W2s[i] = W2[i];
    for (int i = t; i < 64 * 32; i += THREADS) W3s[i] = W3[i];
    if (t < 64) b2s[t] = b2[t];
    int ln = t / 64;
    int j = t % 64;
    int node = blockIdx.x * 4 + ln;
    __syncthreads();
    if (node < N && j < 16) ps[ln][j] = P2[(size_t)node * 16 + j];
    __syncthreads();
    if (node < N) {
        float a = b2s[j];
#pragma unroll
        for (int k = 0; k < 16; ++k) a += ps[ln][k] * W2s[k * 64 + j];
        as[ln][j] = fmaxf(a, 0.0f);
    }
    __syncthreads();
    if (node < N && j < 32) {
        float o = 0.0f;
#pragma unroll
        for (int k = 0; k < 64; ++k) o += as[ln][k] * W3s[k * 32 + j];
        Hb3[(size_t)node * 32 + j] = f2bf(o * dinv[node]);
    }
}

// batch sorted: block g binary-searches its node range, mean over 32 features
__global__ void k_pool_mean(const float* __restrict__ h, const int* __restrict__ batch,
                            int N, float* __restrict__ pooled) {
    int g = blockIdx.x;
    int lo = 0, hi = N;
    while (lo < hi) { int m = (lo + hi) >> 1; if (batch[m] < g) lo = m + 1; else hi = m; }
    int start = lo;
    lo = start; hi = N;
    while (lo < hi) { int m = (lo + hi) >> 1; if (batch[m] < g + 1) lo = m + 1; else hi = m; }
    int end = lo;

    __shared__ float partial[THREADS];
    int f = threadIdx.x % 32;
    int grp = threadIdx.x / 32;
    float acc = 0.0f;
    for (int n = start + grp; n < end; n += 8) acc += h[(size_t)n * 32 + f];
    partial[threadIdx.x] = acc;
    __syncthreads();
    if (threadIdx.x < 32) {
        float s = 0.0f;
#pragma unroll
        for (int tt = 0; tt < 8; ++tt) s += partial[tt * 32 + f];
        int cnt = end - start;
        pooled[g * 32 + f] = s / (float)(cnt > 0 ? cnt : 1);
    }
}

// a = relu(pooled @ Wa + ba) [G,64]; out = tanh(a @ Wo + bo) [G,32]
__global__ void k_head(const float* __restrict__ pooled, const float* __restrict__ Wa,
                       const float* __restrict__ ba, const float* __restrict__ Wo,
                       const float* __restrict__ bo, float* __restrict__ out) {
    int g = blockIdx.x;
    int j = threadIdx.x;  // 64 threads
    __shared__ float p[32];
    __shared__ float a[64];
    if (j < 32) p[j] = pooled[g * 32 + j];
    __syncthreads();
    float acc = ba[j];
#pragma unroll
    for (int k = 0; k < 32; ++k) acc += p[k] * Wa[k * 64 + j];
    a[j] = fmaxf(acc, 0.0f);
    __syncthreads();
    if (j < 32) {
        float acc2 = bo[j];
#pragma unroll
        for (int k = 0; k < 64; ++k) acc2 += a[k] * Wo[k * 32 + j];
        out[g * 32 + j] = tanhf(acc2);
    }
}

static inline int cdiv(long long a, int b) { return (int)((a + b - 1) / b); }
static inline size_t align256(size_t x) { return (x + 255) & ~(size_t)255; }

extern "C" void kernel_launch(void* const* d_in, const int* in_sizes, int n_in,
                              void* d_out, int out_size, void* d_ws, size_t ws_size,
                              hipStream_t stream) {
    const float* x     = (const float*)d_in[0];   // [N,128]
    const int*   edge  = (const int*)d_in[1];     // [2,E]: src row, dst row
    const int*   batch = (const int*)d_in[2];     // [N], sorted
    const float* W1 = (const float*)d_in[3];  const float* b1 = (const float*)d_in[4];
    const float* W2 = (const float*)d_in[5];  const float* b2 = (const float*)d_in[6];
    const float* W3 = (const float*)d_in[7];  const float* b3 = (const float*)d_in[8];
    const float* Wa = (const float*)d_in[9];  const float* ba = (const float*)d_in[10];
    const float* Wo = (const float*)d_in[11]; const float* bo = (const float*)d_in[12];

    const int E = in_sizes[1] / 2;
    const int N = in_sizes[2];
    const int G = 64;
    const int NB = cdiv(N, 1 << BSH);  // 391 for N=100000

    const int* srcp = edge;
    const int* dstp = edge + E;

    // Workspace
    char* base = (char*)d_ws;
    size_t off = 0;
    float* dinv     = (float*)(base + off); off = align256(off + sizeof(float) * N);
    int*   bcnt     = (int*)  (base + off); off = align256(off + sizeof(int) * (NB + 1));
    int*   bbase    = (int*)  (base + off); off = align256(off + sizeof(int) * (NB + 1));
    int*   bcur     = (int*)  (base + off); off = align256(off + sizeof(int) * (NB + 1));
    unsigned int* bedges = (unsigned int*)(base + off); off = align256(off + sizeof(int) * E);
    int*   rowptr   = (int*)  (base + off); off = align256(off + sizeof(int) * (N + 1));
    int*   csr_src  = (int*)  (base + off); off = align256(off + sizeof(int) * E);
    unsigned short* Hb1 = (unsigned short*)(base + off); off = align256(off + sizeof(short) * (size_t)N * 16);
    unsigned short* Hb2 = (unsigned short*)(base + off); off = align256(off + sizeof(short) * (size_t)N * 16);
    float* P2       = (float*)(base + off); off = align256(off + sizeof(float) * (size_t)N * 16);
    unsigned short* Hb3 = (unsigned short*)(base + off); off = align256(off + sizeof(short) * (size_t)N * 32);
    float* h3       = (float*)(base + off); off = align256(off + sizeof(float) * (size_t)N * 32);
    float* pooled   = (float*)(base + off); off = align256(off + sizeof(float) * G * 32);

    // ---- CSR build (binned counting sort, no per-edge global atomics) ----
    k_zero_int<<<cdiv(NB + 1, THREADS), THREADS, 0, stream>>>(bcnt, NB + 1);
    k_bincount<<<cdiv(E, CH_E), THREADS, 0, stream>>>(dstp, bcnt, E, NB);
    k_bucket_scan<<<1, MAXNB, 0, stream>>>(bcnt, bbase, bcur, rowptr, NB, N, E);
    k_binscatter<<<cdiv(E, CH_E), THREADS, 0, stream>>>(srcp, dstp, bcur, bedges, E, NB);
    k_bucket_csr<<<NB, THREADS, 0, stream>>>(bedges, bbase, rowptr, dinv, csr_src, N);

    // ---- Layer 1: Hb1 = bf16((x@W1)*dinv); pull16 -> Hb2 = bf16(relu(.+b1)*dinv) ----
    k_gemm1<<<cdiv(N, 16), THREADS, 0, stream>>>(x, W1, dinv, Hb1, N);
    k_pull<16, 1><<<cdiv(N, 64), THREADS, 0, stream>>>(rowptr, csr_src, dinv, Hb1, b1, Hb2, N);

    // ---- Layer 2 aggregate at input width: P2 = pull16(Hb2) ----
    k_pull<16, 2><<<cdiv(N, 64), THREADS, 0, stream>>>(rowptr, csr_src, dinv, Hb2, b1 /*unused*/, P2, N);

    // ---- Fused node MLP: Hb3 = bf16((relu(P2@W2+b2)@W3)*dinv) ----
    k_mlp<<<cdiv(N, 4), THREADS, 0, stream>>>(P2, W2, b2, W3, dinv, Hb3, N);

    // ---- Layer 3 aggregate: h3 = pull32(Hb3) + b3 ----
    k_pull<32, 0><<<cdiv(N, 32), THREADS, 0, stream>>>(rowptr, csr_src, dinv, Hb3, b3, h3, N);

    // ---- Pool + head ----
    k_pool_mean<<<G, THREADS, 0, stream>>>(h3, batch, N, pooled);
    k_head<<<G, 64, 0, stream>>>(pooled, Wa, ba, Wo, bo, (float*)d_out);
}